// Round 1
// baseline (587.693 us; speedup 1.0000x reference)
//
#include <hip/hip_runtime.h>
#include <hip/hip_bf16.h>
#include <cstdint>

#define NH 6
#define HD 32
#define WSZ 16
#define NTOK 256      // WSZ*WSZ
#define SHIFT_ 8
#define CIN 576       // 3*NH*HD
#define DIMO 192      // NH*HD

// region group for shifted-window mask (H=W=64, ws=16, shift=8):
// rows 0..47 -> 0, 48..55 -> 1, 56..63 -> 2
__device__ __forceinline__ int grp6(int x) { return (x < 48) ? 0 : ((x < 56) ? 1 : 2); }

__device__ __forceinline__ unsigned short f2bf(float f) {
    unsigned int u = __float_as_uint(f);
    u += 0x7fffu + ((u >> 16) & 1u);   // RTNE
    return (unsigned short)(u >> 16);
}

// ---------------- kernel 1: CPB MLP ----------------
// bv[h*961 + p] = 16*sigmoid( sum_j relu(t0*w1[j,0]+t1*w1[j,1]+b1[j]) * w2[h,j] )
__global__ void cpb_kernel(const float* __restrict__ table,
                           const float* __restrict__ w1,
                           const float* __restrict__ b1,
                           const float* __restrict__ w2,
                           float* __restrict__ bv) {
    int id = blockIdx.x * blockDim.x + threadIdx.x;
    if (id >= NH * 961) return;
    int h = id / 961, p = id % 961;
    float t0 = table[2 * p], t1 = table[2 * p + 1];
    const float* w2h = w2 + h * 512;
    float acc = 0.f;
    for (int j = 0; j < 512; ++j) {
        float hid = fmaf(t0, w1[2 * j], fmaf(t1, w1[2 * j + 1], b1[j]));
        hid = fmaxf(hid, 0.f);
        acc = fmaf(hid, w2h[j], acc);
    }
    bv[id] = 16.f / (1.f + __expf(-acc));
}

// ---------------- staging helper ----------------
__device__ __forceinline__ void stage_row(
    int n, int wh, int ww, int b, int h, float scale,
    const float* __restrict__ qkv,
    float* qreg, int* gout, long* pixout,
    float* Ks, unsigned short* Vs, int* Gs)
{
    int i = n >> 4, jj = n & 15;
    int rr = wh * WSZ + i, cc = ww * WSZ + jj;   // coords in rolled frame
    int g = 3 * grp6(rr) + grp6(cc);
    *gout = g;
    int r = (rr + SHIFT_) & 63, c = (cc + SHIFT_) & 63;  // source/dest pixel
    long pix = (long)b * 4096 + (long)(r * 64 + c);
    *pixout = pix;
    const float* basep = qkv + pix * CIN + h * HD;
    // ---- q: keep in registers, fold scale/norm
    {
        const float4* qp = (const float4*)(basep);
        float ss = 0.f;
#pragma unroll
        for (int w = 0; w < 8; ++w) {
            float4 v = qp[w];
            qreg[4 * w + 0] = v.x; qreg[4 * w + 1] = v.y;
            qreg[4 * w + 2] = v.z; qreg[4 * w + 3] = v.w;
        }
#pragma unroll
        for (int d = 0; d < HD; ++d) ss = fmaf(qreg[d], qreg[d], ss);
        float qs = scale / fmaxf(sqrtf(ss), 1e-12f);
#pragma unroll
        for (int d = 0; d < HD; ++d) qreg[d] *= qs;
    }
    // ---- k: normalize -> LDS fp32
    {
        const float4* kp = (const float4*)(basep + DIMO);
        float kr[HD];
        float ss = 0.f;
#pragma unroll
        for (int w = 0; w < 8; ++w) {
            float4 v = kp[w];
            kr[4 * w + 0] = v.x; kr[4 * w + 1] = v.y;
            kr[4 * w + 2] = v.z; kr[4 * w + 3] = v.w;
        }
#pragma unroll
        for (int d = 0; d < HD; ++d) ss = fmaf(kr[d], kr[d], ss);
        float ki = 1.f / fmaxf(sqrtf(ss), 1e-12f);
        float4* kd = (float4*)(Ks + n * HD);
#pragma unroll
        for (int w = 0; w < 8; ++w) {
            float4 v;
            v.x = kr[4 * w + 0] * ki; v.y = kr[4 * w + 1] * ki;
            v.z = kr[4 * w + 2] * ki; v.w = kr[4 * w + 3] * ki;
            kd[w] = v;
        }
    }
    // ---- v: -> LDS bf16
    {
        const float4* vp = (const float4*)(basep + 2 * DIMO);
        float vr[HD];
#pragma unroll
        for (int w = 0; w < 8; ++w) {
            float4 v = vp[w];
            vr[4 * w + 0] = v.x; vr[4 * w + 1] = v.y;
            vr[4 * w + 2] = v.z; vr[4 * w + 3] = v.w;
        }
        uint4* vd = (uint4*)(Vs + n * HD);
#pragma unroll
        for (int w = 0; w < 4; ++w) {
            uint4 u;
            u.x = (unsigned)f2bf(vr[8 * w + 0]) | ((unsigned)f2bf(vr[8 * w + 1]) << 16);
            u.y = (unsigned)f2bf(vr[8 * w + 2]) | ((unsigned)f2bf(vr[8 * w + 3]) << 16);
            u.z = (unsigned)f2bf(vr[8 * w + 4]) | ((unsigned)f2bf(vr[8 * w + 5]) << 16);
            u.w = (unsigned)f2bf(vr[8 * w + 6]) | ((unsigned)f2bf(vr[8 * w + 7]) << 16);
            vd[w] = u;
        }
    }
    Gs[n] = g;
}

// ---------------- kernel 2: attention ----------------
// grid: 256 windows * 6 heads blocks, 128 threads; thread t owns query rows t and t+128
__global__ __launch_bounds__(128, 2) void attn_kernel(
    const float* __restrict__ qkv,
    const float* __restrict__ logit_scale,
    const float* __restrict__ bv,
    float* __restrict__ out)
{
    __shared__ __align__(16) float Ks[NTOK * HD];           // 32 KB normalized K
    __shared__ __align__(16) unsigned short Vs[NTOK * HD];  // 16 KB bf16 V
    __shared__ float Bv[961];                               // per-head 31x31 bias grid
    __shared__ int Gs[NTOK];                                // mask group per token

    const int t = threadIdx.x;
    const int h = blockIdx.x % NH;
    const int win = blockIdx.x / NH;
    const int b = win >> 4;
    const int wl = win & 15;
    const int wh = wl >> 2, ww = wl & 3;

    const float scale = __expf(fminf(logit_scale[h], 4.6051702f));  // min(ls, log 100)

    for (int p = t; p < 961; p += 128) Bv[p] = bv[h * 961 + p];

    float q0[HD], q1[HD];
    int g0, g1;
    long pix0, pix1;
    stage_row(t,       wh, ww, b, h, scale, qkv, q0, &g0, &pix0, Ks, Vs, Gs);
    stage_row(t + 128, wh, ww, b, h, scale, qkv, q1, &g1, &pix1, Ks, Vs, Gs);

    __syncthreads();

    const int i0 = t >> 4, j0 = t & 15;
    const int base0 = (i0 + 15) * 31 + (j0 + 15);
    const int base1 = base0 + 8 * 31;   // row1 is i0+8, same j

    float o0[HD], o1[HD];
#pragma unroll
    for (int d = 0; d < HD; ++d) { o0[d] = 0.f; o1[d] = 0.f; }
    float l0 = 0.f, l1 = 0.f;

    const float4* Ks4 = (const float4*)Ks;
    const uint4*  Vs4 = (const uint4*)Vs;

    for (int m = 0; m < NTOK; ++m) {
        float4 k4[8];
#pragma unroll
        for (int w = 0; w < 8; ++w) k4[w] = Ks4[m * 8 + w];
        float d0a = 0.f, d0b = 0.f, d1a = 0.f, d1b = 0.f;
#pragma unroll
        for (int w = 0; w < 8; ++w) {
            d0a = fmaf(q0[4 * w + 0], k4[w].x, d0a);
            d0b = fmaf(q0[4 * w + 1], k4[w].y, d0b);
            d0a = fmaf(q0[4 * w + 2], k4[w].z, d0a);
            d0b = fmaf(q0[4 * w + 3], k4[w].w, d0b);
            d1a = fmaf(q1[4 * w + 0], k4[w].x, d1a);
            d1b = fmaf(q1[4 * w + 1], k4[w].y, d1b);
            d1a = fmaf(q1[4 * w + 2], k4[w].z, d1a);
            d1b = fmaf(q1[4 * w + 3], k4[w].w, d1b);
        }
        // bias: index[n][m] = (i_n-i_m+15)*31 + (j_n-j_m+15) = base_n - (m + 15*(m>>4))
        int off = m + ((m >> 4) * 15);
        float bb0 = Bv[base0 - off];
        float bb1 = Bv[base1 - off];
        int gm = Gs[m];
        float s0 = d0a + d0b + bb0 + ((gm == g0) ? 0.f : -100.f);
        float s1 = d1a + d1b + bb1 + ((gm == g1) ? 0.f : -100.f);
        // logits <= 10*cos + 16 <= 26 -> static shift, no online max needed
        float p0 = __expf(s0 - 26.f);
        float p1 = __expf(s1 - 26.f);
        l0 += p0; l1 += p1;
        uint4 vv[4];
#pragma unroll
        for (int w = 0; w < 4; ++w) vv[w] = Vs4[m * 4 + w];
#pragma unroll
        for (int w = 0; w < 4; ++w) {
            unsigned int ua = vv[w].x, ub = vv[w].y, uc = vv[w].z, ud = vv[w].w;
            float f0 = __uint_as_float(ua << 16);
            float f1 = __uint_as_float(ua & 0xffff0000u);
            float f2 = __uint_as_float(ub << 16);
            float f3 = __uint_as_float(ub & 0xffff0000u);
            float f4 = __uint_as_float(uc << 16);
            float f5 = __uint_as_float(uc & 0xffff0000u);
            float f6 = __uint_as_float(ud << 16);
            float f7 = __uint_as_float(ud & 0xffff0000u);
            o0[8 * w + 0] = fmaf(p0, f0, o0[8 * w + 0]);
            o0[8 * w + 1] = fmaf(p0, f1, o0[8 * w + 1]);
            o0[8 * w + 2] = fmaf(p0, f2, o0[8 * w + 2]);
            o0[8 * w + 3] = fmaf(p0, f3, o0[8 * w + 3]);
            o0[8 * w + 4] = fmaf(p0, f4, o0[8 * w + 4]);
            o0[8 * w + 5] = fmaf(p0, f5, o0[8 * w + 5]);
            o0[8 * w + 6] = fmaf(p0, f6, o0[8 * w + 6]);
            o0[8 * w + 7] = fmaf(p0, f7, o0[8 * w + 7]);
            o1[8 * w + 0] = fmaf(p1, f0, o1[8 * w + 0]);
            o1[8 * w + 1] = fmaf(p1, f1, o1[8 * w + 1]);
            o1[8 * w + 2] = fmaf(p1, f2, o1[8 * w + 2]);
            o1[8 * w + 3] = fmaf(p1, f3, o1[8 * w + 3]);
            o1[8 * w + 4] = fmaf(p1, f4, o1[8 * w + 4]);
            o1[8 * w + 5] = fmaf(p1, f5, o1[8 * w + 5]);
            o1[8 * w + 6] = fmaf(p1, f6, o1[8 * w + 6]);
            o1[8 * w + 7] = fmaf(p1, f7, o1[8 * w + 7]);
        }
    }

    float inv0 = 1.f / l0, inv1 = 1.f / l1;
    {
        float4* op = (float4*)(out + pix0 * DIMO + h * HD);
#pragma unroll
        for (int w = 0; w < 8; ++w) {
            float4 v;
            v.x = o0[4 * w + 0] * inv0; v.y = o0[4 * w + 1] * inv0;
            v.z = o0[4 * w + 2] * inv0; v.w = o0[4 * w + 3] * inv0;
            op[w] = v;
        }
    }
    {
        float4* op = (float4*)(out + pix1 * DIMO + h * HD);
#pragma unroll
        for (int w = 0; w < 8; ++w) {
            float4 v;
            v.x = o1[4 * w + 0] * inv1; v.y = o1[4 * w + 1] * inv1;
            v.z = o1[4 * w + 2] * inv1; v.w = o1[4 * w + 3] * inv1;
            op[w] = v;
        }
    }
}

extern "C" void kernel_launch(void* const* d_in, const int* in_sizes, int n_in,
                              void* d_out, int out_size, void* d_ws, size_t ws_size,
                              hipStream_t stream) {
    const float* qkv         = (const float*)d_in[0];
    const float* table       = (const float*)d_in[1];
    // d_in[2] = mask   : recomputed on the fly from window-region groups
    const float* logit_scale = (const float*)d_in[3];
    const float* w1          = (const float*)d_in[4];
    const float* b1          = (const float*)d_in[5];
    const float* w2          = (const float*)d_in[6];
    // d_in[7] = index  : recomputed on the fly from relative coords
    float* out = (float*)d_out;
    float* bv  = (float*)d_ws;   // 6*961 floats = 23 KB

    cpb_kernel<<<(NH * 961 + 255) / 256, 256, 0, stream>>>(table, w1, b1, w2, bv);
    attn_kernel<<<256 * NH, 128, 0, stream>>>(qkv, logit_scale, bv, out);
}

// Round 2
// 264.768 us; speedup vs baseline: 2.2197x; 2.2197x over previous
//
#include <hip/hip_runtime.h>
#include <cstdint>

#define NH 6
#define HD 32
#define NTOK 256
#define CIN 576
#define DIMO 192
#define LOG2E 1.44269504f
#define SHIFT2 37.6f
#define MNEG (-144.269504f)   // -100 * log2(e)

typedef short short8 __attribute__((ext_vector_type(8)));
typedef float f32x4 __attribute__((ext_vector_type(4)));

__device__ __forceinline__ int grp6(int x) { return (x < 48) ? 0 : ((x < 56) ? 1 : 2); }

__device__ __forceinline__ unsigned short f2bf(float f) {
    unsigned int u = __float_as_uint(f);
    u += 0x7fffu + ((u >> 16) & 1u);   // RTNE
    return (unsigned short)(u >> 16);
}
__device__ __forceinline__ float bf2f(unsigned short s) {
    return __uint_as_float(((unsigned)s) << 16);
}

// ---------------- kernel 1: CPB MLP (block per table point) ----------------
__global__ void cpb_kernel(const float* __restrict__ table,
                           const float* __restrict__ w1,
                           const float* __restrict__ b1,
                           const float* __restrict__ w2,
                           float* __restrict__ bv) {
    __shared__ float hid[512];
    int p = blockIdx.x;                 // 0..960
    float t0 = table[2 * p], t1 = table[2 * p + 1];
    int t = threadIdx.x;                // 256 threads
    for (int j = t; j < 512; j += 256) {
        float hv = fmaf(t0, w1[2 * j], fmaf(t1, w1[2 * j + 1], b1[j]));
        hid[j] = fmaxf(hv, 0.f);
    }
    __syncthreads();
    if (t < 192) {
        int h = t >> 5, l = t & 31;
        const float* w2h = w2 + h * 512;
        float acc = 0.f;
        for (int j = l; j < 512; j += 32) acc = fmaf(hid[j], w2h[j], acc);
        acc += __shfl_xor(acc, 1, 32);
        acc += __shfl_xor(acc, 2, 32);
        acc += __shfl_xor(acc, 4, 32);
        acc += __shfl_xor(acc, 8, 32);
        acc += __shfl_xor(acc, 16, 32);
        if (l == 0) bv[h * 961 + p] = (16.f / (1.f + __expf(-acc))) * LOG2E;
    }
}

// ---------------- kernel 2: MFMA attention ----------------
// block = one (window, head), 512 threads = 8 waves; wave w owns q-rows [w*32, w*32+32)
__global__ __launch_bounds__(512, 4) void attn_kernel(
    const float* __restrict__ qkv,
    const float* __restrict__ logit_scale,
    const float* __restrict__ bv,
    float* __restrict__ out)
{
    __shared__ __align__(16) short Qb[NTOK * HD];   // 16 KB  Q bf16, scale*log2e folded
    __shared__ __align__(16) short Kb[NTOK * HD];   // 16 KB  K bf16 normalized
    __shared__ __align__(16) short Vt[HD * 264];    // 16.9 KB V^T, stride 264 (16B-aligned rows)
    __shared__ __align__(16) short P[8 * 32 * 32];  // 16 KB  per-wave P staging (C->A layout)
    __shared__ float Bv[961];                       // bias grid * log2e

    const int t = threadIdx.x;
    const int h = blockIdx.x % NH;
    const int win = blockIdx.x / NH;
    const int b = win >> 4, wl = win & 15, wh = wl >> 2, ww = wl & 3;

    const float scale2 = __expf(fminf(logit_scale[h], 4.6051702f)) * LOG2E;

    for (int p = t; p < 961; p += 512) Bv[p] = bv[h * 961 + p];

    // ---- staging: threads 0..255 do Q,K; 256..511 do V^T
    {
        int n = (t < 256) ? t : (t - 256);
        int i = n >> 4, j = n & 15;
        int rr = wh * 16 + i, cc = ww * 16 + j;
        int r = (rr + 8) & 63, c = (cc + 8) & 63;
        const float* base = qkv + ((long)(b * 4096 + r * 64 + c)) * CIN + h * HD;
        if (t < 256) {
            float qv[32], kv[32];
            const float4* qp = (const float4*)base;
            const float4* kp = (const float4*)(base + DIMO);
#pragma unroll
            for (int w = 0; w < 8; ++w) {
                float4 x = qp[w];
                qv[4 * w + 0] = x.x; qv[4 * w + 1] = x.y; qv[4 * w + 2] = x.z; qv[4 * w + 3] = x.w;
            }
#pragma unroll
            for (int w = 0; w < 8; ++w) {
                float4 x = kp[w];
                kv[4 * w + 0] = x.x; kv[4 * w + 1] = x.y; kv[4 * w + 2] = x.z; kv[4 * w + 3] = x.w;
            }
            float sq = 0.f, sk = 0.f;
#pragma unroll
            for (int d = 0; d < 32; ++d) { sq = fmaf(qv[d], qv[d], sq); sk = fmaf(kv[d], kv[d], sk); }
            float qs = scale2 / fmaxf(sqrtf(sq), 1e-12f);
            float ks = 1.f / fmaxf(sqrtf(sk), 1e-12f);
#pragma unroll
            for (int w = 0; w < 4; ++w) {
                short8 qc, kc;
#pragma unroll
                for (int e = 0; e < 8; ++e) {
                    qc[e] = (short)f2bf(qv[8 * w + e] * qs);
                    kc[e] = (short)f2bf(kv[8 * w + e] * ks);
                }
                *(short8*)&Qb[n * 32 + 8 * w] = qc;
                *(short8*)&Kb[n * 32 + 8 * w] = kc;
            }
        } else {
            float vv[32];
            const float4* vp = (const float4*)(base + 2 * DIMO);
#pragma unroll
            for (int w = 0; w < 8; ++w) {
                float4 x = vp[w];
                vv[4 * w + 0] = x.x; vv[4 * w + 1] = x.y; vv[4 * w + 2] = x.z; vv[4 * w + 3] = x.w;
            }
#pragma unroll
            for (int d = 0; d < 32; ++d) Vt[d * 264 + n] = (short)f2bf(vv[d]);
        }
    }
    __syncthreads();

    // ---- per-wave MFMA flash loop
    const int wv = t >> 6, lane = t & 63, quad = lane >> 4, l15 = lane & 15;
    short* Pw = P + wv * 1024;

    int trg[2];
    short8 aQ[2];
#pragma unroll
    for (int tl = 0; tl < 2; ++tl) {
        trg[tl] = wv * 2 + tl;
        aQ[tl] = *(const short8*)&Qb[(trg[tl] * 16 + l15) * 32 + quad * 8];
    }
    int gqi[2];
#pragma unroll
    for (int tl = 0; tl < 2; ++tl) gqi[tl] = grp6(wh * 16 + trg[tl]);
    int gqj[4];
#pragma unroll
    for (int reg = 0; reg < 4; ++reg) gqj[reg] = grp6(ww * 16 + quad * 4 + reg);
    const int gmj = grp6(ww * 16 + l15);

    f32x4 O[2][2];
    float lp[2][4];
#pragma unroll
    for (int tl = 0; tl < 2; ++tl)
#pragma unroll
        for (int dtk = 0; dtk < 2; ++dtk) O[tl][dtk] = (f32x4){0.f, 0.f, 0.f, 0.f};
#pragma unroll
    for (int tl = 0; tl < 2; ++tl)
#pragma unroll
        for (int reg = 0; reg < 4; ++reg) lp[tl][reg] = 0.f;

    const f32x4 Zero = (f32x4){0.f, 0.f, 0.f, 0.f};

    for (int c = 0; c < 8; ++c) {
        // S = Q * K^T for 2x2 tiles (keys c*32 .. c*32+31)
        short8 bK[2];
        int gmi[2], ctg[2];
#pragma unroll
        for (int ct = 0; ct < 2; ++ct) {
            ctg[ct] = c * 2 + ct;
            bK[ct] = *(const short8*)&Kb[(ctg[ct] * 16 + l15) * 32 + quad * 8];
            gmi[ct] = grp6(wh * 16 + ctg[ct]);
        }
        f32x4 S[2][2];
#pragma unroll
        for (int tl = 0; tl < 2; ++tl)
#pragma unroll
            for (int ct = 0; ct < 2; ++ct)
                S[tl][ct] = __builtin_amdgcn_mfma_f32_16x16x32_bf16(aQ[tl], bK[ct], Zero, 0, 0, 0);

        // epilogue: bias + mask + exp2, pack to bf16 P (per-wave private region)
#pragma unroll
        for (int tl = 0; tl < 2; ++tl) {
#pragma unroll
            for (int ct = 0; ct < 2; ++ct) {
                int rbase = (trg[tl] - ctg[ct] + 15) * 31 + 15 - l15;
                bool mi = (gqi[tl] == gmi[ct]);
#pragma unroll
                for (int reg = 0; reg < 4; ++reg) {
                    float bias = Bv[rbase + quad * 4 + reg];
                    float mterm = (mi && (gqj[reg] == gmj)) ? 0.f : MNEG;
                    float arg = S[tl][ct][reg] + bias + mterm - SHIFT2;
                    float e = __builtin_amdgcn_exp2f(arg);
                    unsigned short pb = f2bf(e);
                    lp[tl][reg] += bf2f(pb);
                    Pw[(tl * 16 + quad * 4 + reg) * 32 + ct * 16 + l15] = (short)pb;
                }
            }
        }

        // PV: O += P * V  (K=32 chunk)
        short8 aP[2], bV[2];
#pragma unroll
        for (int tl = 0; tl < 2; ++tl)
            aP[tl] = *(const short8*)&Pw[(tl * 16 + l15) * 32 + quad * 8];
#pragma unroll
        for (int dtk = 0; dtk < 2; ++dtk)
            bV[dtk] = *(const short8*)&Vt[(dtk * 16 + l15) * 264 + c * 32 + quad * 8];
#pragma unroll
        for (int tl = 0; tl < 2; ++tl)
#pragma unroll
            for (int dtk = 0; dtk < 2; ++dtk)
                O[tl][dtk] = __builtin_amdgcn_mfma_f32_16x16x32_bf16(aP[tl], bV[dtk], O[tl][dtk], 0, 0, 0);
    }

    // row-sum reduce across the 16 lanes of each quad (lands in C-layout lanes)
#pragma unroll
    for (int tl = 0; tl < 2; ++tl)
#pragma unroll
        for (int reg = 0; reg < 4; ++reg) {
            float s = lp[tl][reg];
            s += __shfl_xor(s, 1, 16);
            s += __shfl_xor(s, 2, 16);
            s += __shfl_xor(s, 4, 16);
            s += __shfl_xor(s, 8, 16);
            lp[tl][reg] = 1.f / s;
        }

    // store (window-reverse + unshift folded into pixel calc)
    const long pixb = (long)b * 4096;
#pragma unroll
    for (int tl = 0; tl < 2; ++tl) {
        int r = (wh * 16 + trg[tl] + 8) & 63;
#pragma unroll
        for (int reg = 0; reg < 4; ++reg) {
            int cpix = (ww * 16 + quad * 4 + reg + 8) & 63;
            float* op = out + (pixb + r * 64 + cpix) * DIMO + h * HD + l15;
            float inv = lp[tl][reg];
            op[0]  = O[tl][0][reg] * inv;
            op[16] = O[tl][1][reg] * inv;
        }
    }
}

extern "C" void kernel_launch(void* const* d_in, const int* in_sizes, int n_in,
                              void* d_out, int out_size, void* d_ws, size_t ws_size,
                              hipStream_t stream) {
    const float* qkv         = (const float*)d_in[0];
    const float* table       = (const float*)d_in[1];
    // d_in[2] = mask   : recomputed from window-region groups
    const float* logit_scale = (const float*)d_in[3];
    const float* w1          = (const float*)d_in[4];
    const float* b1          = (const float*)d_in[5];
    const float* w2          = (const float*)d_in[6];
    // d_in[7] = index  : recomputed from relative coords
    float* out = (float*)d_out;
    float* bv  = (float*)d_ws;   // 6*961 floats

    cpb_kernel<<<961, 256, 0, stream>>>(table, w1, b1, w2, bv);
    attn_kernel<<<256 * NH, 512, 0, stream>>>(qkv, logit_scale, bv, out);
}